// Round 9
// baseline (166.837 us; speedup 1.0000x reference)
//
#include <hip/hip_runtime.h>

// Problem constants
#define NBOOKS 4
#define CODES  1024
#define DIM    64
#define NPOS   32768          // B*T*H*W
#define CCH    256            // NB*DIM (channel dim of z)
#define ENC_OFF  8388608
#define LOSS_OFF 8519680
#define PERP_OFF 8519681

// workspace byte offsets
#define WS_E2      0              // 4096 f32 (raw ||e||^2)
#define WS_EHI     16384          // 4096*64 f16 = 512 KB  (hi of -2*e)
#define WS_ELO     540672         // 512 KB                 (lo of -2*e)
#define WS_IDX     1064960        // 131072 int
#define WS_CNT     1589248        // 4096 int
#define WS_PART    1605632        // 128 f32
#define WS_FLAGCNT 1607680        // 1 int
#define WS_FLAGS   1607696        // 131072 int

typedef _Float16 f16x8 __attribute__((ext_vector_type(8)));
typedef _Float16 f16x4 __attribute__((ext_vector_type(4)));
typedef float    f32x4 __attribute__((ext_vector_type(4)));

// ------------------------------------------- prep: e2, hi/lo f16(-2e), zeroing
__global__ void k_eprep2(const float* __restrict__ emb, float* __restrict__ e2,
                         _Float16* __restrict__ ehi, _Float16* __restrict__ elo,
                         int* __restrict__ counts, int* __restrict__ flagcnt) {
    int i = blockIdx.x * 256 + threadIdx.x;            // row 0..4095 = k*1024+c
    counts[i] = 0;
    if (i == 0) *flagcnt = 0;
    const float4* e = (const float4*)(emb + ((size_t)i << 6));
    _Float16* hp = ehi + ((size_t)i << 6);
    _Float16* lp = elo + ((size_t)i << 6);
    float s = 0.f;
#pragma unroll
    for (int j = 0; j < 16; ++j) {
        float4 v = e[j];
        s += v.x * v.x + v.y * v.y + v.z * v.z + v.w * v.w;
        f16x4 hv, lv;
        float m;
        m = -2.f * v.x; hv[0] = (_Float16)m; lv[0] = (_Float16)(m - (float)hv[0]);
        m = -2.f * v.y; hv[1] = (_Float16)m; lv[1] = (_Float16)(m - (float)hv[1]);
        m = -2.f * v.z; hv[2] = (_Float16)m; lv[2] = (_Float16)(m - (float)hv[2]);
        m = -2.f * v.w; hv[3] = (_Float16)m; lv[3] = (_Float16)(m - (float)hv[3]);
        *(f16x4*)&hp[j * 4] = hv;
        *(f16x4*)&lp[j * 4] = lv;
    }
    e2[i] = s;           // raw; argmin adds per-position (||x||^2 + 1)
}

// ---------------------------------------------------------------- MFMA argmin v5
// Block = 256 positions x all 1024 codes, one book. X direct global->regs.
// acc init = e2 + ||x||^2 + 1  ->  acc IS (true squared distance + 1): small
// positive magnitude => 64-ulp key granule ~1e-3, so near-tie margin is tight
// and few positions get flagged for exact rescore.
// E streamed in 32-code chunks (8 KB hi+lo), 3-buffer, 1 barrier/chunk,
// XOR-swizzled write+read. Packed key = (score_bits & ~63) | kit.
__global__ void __launch_bounds__(256, 2) k_argmin_mfma(
        const float* __restrict__ z, const float* __restrict__ e2g,
        const _Float16* __restrict__ ehi, const _Float16* __restrict__ elo,
        int* __restrict__ idxbuf, int* __restrict__ flagcnt,
        int* __restrict__ flaglist) {
    __shared__ __attribute__((aligned(16))) char sE[3][8192];  // hi[0,4K) lo[4K,8K)

    int tid = threadIdx.x;
    int wave = tid >> 6, lane = tid & 63;
    int lrow = lane >> 4, lcol = lane & 15;
    int k = blockIdx.y;
    int posbase = blockIdx.x * 256;
    int b = posbase >> 13, s0 = posbase & 8191;
    int wb = wave * 64;

    // ---- X fragments straight into registers + per-position ||x||^2
    const float* zb = z + (((size_t)(b * CCH + k * DIM)) << 13) + s0 + wb;
    f16x8 Xh[4][2], Xl[4][2];
    float X2[4];                          // will hold ||x||^2 + 1 for pos pt*16+lcol
#pragma unroll
    for (int pt = 0; pt < 4; ++pt) {
        float sq = 0.f;
#pragma unroll
        for (int kc = 0; kc < 2; ++kc) {
            f16x8 hv, lv;
#pragma unroll
            for (int e = 0; e < 8; ++e) {
                int d = kc * 32 + lrow * 8 + e;
                float f = zb[((size_t)d << 13) + pt * 16 + lcol];
                sq = fmaf(f, f, sq);
                _Float16 h = (_Float16)f;
                hv[e] = h;
                lv[e] = (_Float16)(f - (float)h);
            }
            Xh[pt][kc] = hv; Xl[pt][kc] = lv;
        }
        // sum partial ||x||^2 across the 4 lrow lanes of this position
        sq += __shfl_xor(sq, 16);
        sq += __shfl_xor(sq, 32);
        X2[pt] = sq + 1.0f;
    }

    // ---- E staging params: thread moves 32 B (two swizzled 16B pieces)/chunk
    int half = tid >> 7;                  // 0: hi, 1: lo
    int u = tid & 127;
    int r = u >> 2, q = u & 3;            // code row 0..31, 32B quarter 0..3
    const char* bookh = (const char*)((half ? elo : ehi) + ((size_t)k << 16));
    const char* src0 = bookh + r * 128 + q * 32;          // + chunk*4096
    int c0 = 2 * q, c1 = 2 * q + 1;
    int w0 = half * 4096 + r * 128 + ((c0 ^ (r & 7)) << 4);
    int w1 = half * 4096 + r * 128 + ((c1 ^ (r & 7)) << 4);

    const float* e2k = e2g + (k << 10);

    // prologue: stage chunk 0 into buffer 0
    {
        f16x8 v0 = *(const f16x8*)(src0);
        f16x8 v1 = *(const f16x8*)(src0 + 16);
        *(f16x8*)&sE[0][w0] = v0;
        *(f16x8*)&sE[0][w1] = v1;
    }

    unsigned m1[4][4], m2[4][4];
#pragma unroll
    for (int pt = 0; pt < 4; ++pt)
#pragma unroll
        for (int rr = 0; rr < 4; ++rr) { m1[pt][rr] = 0x7F7FFFFFu; m2[pt][rr] = 0x7F7FFFFFu; }

    int sx = (lcol & 7) << 4;
    int o0 = (lrow << 4) ^ sx;            // K-chunk 0 (dims 0..31)
    int o1 = ((4 + lrow) << 4) ^ sx;      // K-chunk 1 (dims 32..63)
    int rbase = lcol << 7;                // code row stride 128 B (+ st*2048)

    int cur = 0, nxt = 1, fre = 2;
    for (int it = 0; it < 32; ++it) {
        f16x8 nv0, nv1;
        bool has = it < 31;
        if (has) {
            const char* sp = src0 + (size_t)(it + 1) * 4096;
            nv0 = *(const f16x8*)(sp);
            nv1 = *(const f16x8*)(sp + 16);
        }
        __syncthreads();
        const char* sc = sE[cur];
#pragma unroll
        for (int st = 0; st < 2; ++st) {
            f32x4 e2v = *(const f32x4*)(e2k + it * 32 + st * 16 + lrow * 4);
            const char* rb = sc + st * 2048 + rbase;
            f16x8 eh0 = *(const f16x8*)(rb + o0);
            f16x8 eh1 = *(const f16x8*)(rb + o1);
            f16x8 el0 = *(const f16x8*)(rb + 4096 + o0);
            f16x8 el1 = *(const f16x8*)(rb + 4096 + o1);
            unsigned kit = (unsigned)(it * 2 + st);
#pragma unroll
            for (int pt = 0; pt < 4; ++pt) {
                f32x4 acc = e2v + X2[pt];     // score = ||x-e||^2 + 1 (positive)
                acc = __builtin_amdgcn_mfma_f32_16x16x32_f16(eh0, Xh[pt][0], acc, 0, 0, 0);
                acc = __builtin_amdgcn_mfma_f32_16x16x32_f16(eh0, Xl[pt][0], acc, 0, 0, 0);
                acc = __builtin_amdgcn_mfma_f32_16x16x32_f16(el0, Xh[pt][0], acc, 0, 0, 0);
                acc = __builtin_amdgcn_mfma_f32_16x16x32_f16(eh1, Xh[pt][1], acc, 0, 0, 0);
                acc = __builtin_amdgcn_mfma_f32_16x16x32_f16(eh1, Xl[pt][1], acc, 0, 0, 0);
                acc = __builtin_amdgcn_mfma_f32_16x16x32_f16(el1, Xh[pt][1], acc, 0, 0, 0);
#pragma unroll
                for (int rr = 0; rr < 4; ++rr) {
                    unsigned key = (__float_as_uint(acc[rr]) & 0xFFFFFFC0u) | kit;
                    unsigned mx = key > m1[pt][rr] ? key : m1[pt][rr];
                    m2[pt][rr] = m2[pt][rr] < mx ? m2[pt][rr] : mx;
                    m1[pt][rr] = m1[pt][rr] < key ? m1[pt][rr] : key;
                }
            }
        }
        if (has) {
            *(f16x8*)&sE[nxt][w0] = nv0;
            *(f16x8*)&sE[nxt][w1] = nv1;
        }
        int t = cur; cur = nxt; nxt = fre; fre = t;
    }

    // ---- within-thread merge over r slots (exact, index tie-break)
    float F1[4], F2[4]; int I1[4];
#pragma unroll
    for (int pt = 0; pt < 4; ++pt) {
        float f1 = 3.4e38f, f2 = 3.4e38f; int i1 = 0;
#pragma unroll
        for (int rr = 0; rr < 4; ++rr) {
            float f = __uint_as_float(m1[pt][rr] & 0xFFFFFFC0u);
            int   c = (int)(m1[pt][rr] & 63u) * 16 + lrow * 4 + rr;
            float g = __uint_as_float(m2[pt][rr] & 0xFFFFFFC0u);
            bool take = (f < f1) || (f == f1 && c < i1);
            float loser = take ? f1 : f;
            f2 = fminf(fminf(f2, g), loser);
            if (take) { f1 = f; i1 = c; }
        }
        F1[pt] = f1; F2[pt] = f2; I1[pt] = i1;
    }

    // ---- merge across lrow groups (4 lanes hold same position)
#pragma unroll
    for (int off = 16; off < 64; off <<= 1) {
#pragma unroll
        for (int pt = 0; pt < 4; ++pt) {
            float om1 = __shfl_xor(F1[pt], off);
            float om2 = __shfl_xor(F2[pt], off);
            int   oi  = __shfl_xor(I1[pt], off);
            bool take = (om1 < F1[pt]) || (om1 == F1[pt] && oi < I1[pt]);
            float loser = take ? F1[pt] : om1;
            F2[pt] = fminf(fminf(F2[pt], om2), loser);
            if (take) { F1[pt] = om1; I1[pt] = oi; }
        }
    }

    // ---- write idx, flag near-ties: adaptive margin
    //      thr = 2*key-granule(F1) + compute-error slack
    //      granule = 64*ulp(F1) <= F1*7.63e-6
    if (lane < 16) {
#pragma unroll
        for (int pt = 0; pt < 4; ++pt) {
            int n = posbase + wb + pt * 16 + lane;
            idxbuf[(k << 15) + n] = I1[pt];
            float thr = fmaf(F1[pt], 3.2e-5f, 2.0e-3f);
            if (F2[pt] - F1[pt] < thr) {
                int slot = atomicAdd(flagcnt, 1);
                flaglist[slot] = (k << 15) + n;
            }
        }
    }
}

// ---------------------------------------------------------------- rescore v2
// 8 flagged positions per block, half-wave (32 lanes) per position, 32 codes
// per lane. E via float4 loads, 2 codes x 4 accumulators in flight.
__global__ void __launch_bounds__(256) k_rescore(
        const float* __restrict__ z, const float* __restrict__ emb,
        const float* __restrict__ e2g, const int* __restrict__ flagcnt,
        const int* __restrict__ flaglist, int* __restrict__ idxbuf) {
    __shared__ __attribute__((aligned(16))) float xsh[8][64];
    __shared__ int meta[8];
    int tid = threadIdx.x;
    int nf = *flagcnt;
    for (int base = blockIdx.x * 8; base < nf; base += gridDim.x * 8) {
        if (tid < 8) meta[tid] = (base + tid < nf) ? flaglist[base + tid] : -1;
        __syncthreads();
        for (int j = tid; j < 512; j += 256) {
            int p = j >> 6, d = j & 63;
            int gp = meta[p];
            if (gp >= 0) {
                int kk = gp >> 15, n = gp & 32767;
                int bb = n >> 13, s = n & 8191;
                xsh[p][d] = z[(((size_t)(bb * CCH + kk * DIM + d)) << 13) + s];
            }
        }
        __syncthreads();
        int p = tid >> 5, cg = tid & 31;
        int gp = meta[p];
        float best = 3.4e38f; int bi = 0x7FFFFFFF;
        if (gp >= 0) {
            int kk = gp >> 15;
            const f32x4* ek4 = (const f32x4*)(emb + ((size_t)kk << 16));
            const float*  ee = e2g + (kk << 10);
            const f32x4* xr4 = (const f32x4*)xsh[p];
            for (int c = cg * 32; c < cg * 32 + 32; c += 2) {
                const f32x4* ev0 = ek4 + (size_t)c * 16;
                const f32x4* ev1 = ev0 + 16;
                float a00 = 0.f, a01 = 0.f, a02 = 0.f, a03 = 0.f;
                float a10 = 0.f, a11 = 0.f, a12 = 0.f, a13 = 0.f;
#pragma unroll
                for (int j = 0; j < 16; ++j) {
                    f32x4 xv = xr4[j];
                    f32x4 q0 = ev0[j];
                    f32x4 q1 = ev1[j];
                    a00 = fmaf(xv[0], q0[0], a00); a01 = fmaf(xv[1], q0[1], a01);
                    a02 = fmaf(xv[2], q0[2], a02); a03 = fmaf(xv[3], q0[3], a03);
                    a10 = fmaf(xv[0], q1[0], a10); a11 = fmaf(xv[1], q1[1], a11);
                    a12 = fmaf(xv[2], q1[2], a12); a13 = fmaf(xv[3], q1[3], a13);
                }
                float d0 = fmaf(-2.f, (a00 + a01) + (a02 + a03), ee[c]);
                float d1 = fmaf(-2.f, (a10 + a11) + (a12 + a13), ee[c + 1]);
                if (d0 < best) { best = d0; bi = c; }       // strict <, ascending c
                if (d1 < best) { best = d1; bi = c + 1; }
            }
        }
#pragma unroll
        for (int off = 1; off < 32; off <<= 1) {
            float ob = __shfl_xor(best, off, 32);
            int   oi = __shfl_xor(bi, off, 32);
            if (ob < best || (ob == best && oi < bi)) { best = ob; bi = oi; }
        }
        if (cg == 0 && gp >= 0) idxbuf[gp] = bi;
        __syncthreads();
    }
}

// ---------------------------------------------------------------- gather+loss
// 4 consecutive positions per thread -> float4 z loads / q stores.
__global__ void __launch_bounds__(256) k_quant(
        const float* __restrict__ z, const float* __restrict__ emb,
        const int* __restrict__ idxbuf, float* __restrict__ out,
        int* __restrict__ counts, float* __restrict__ partial) {
    int tid = threadIdx.x;
    int q = blockIdx.x * 256 + tid;       // quad index
    int n0 = q * 4;
    int k = blockIdx.y;
    int b = n0 >> 13;
    int s = n0 & 8191;

    int4 bi = *(const int4*)&idxbuf[(k << 15) + n0];
    const f32x4* e0 = (const f32x4*)(emb + ((size_t)k << 16) + ((size_t)bi.x << 6));
    const f32x4* e1 = (const f32x4*)(emb + ((size_t)k << 16) + ((size_t)bi.y << 6));
    const f32x4* e2 = (const f32x4*)(emb + ((size_t)k << 16) + ((size_t)bi.z << 6));
    const f32x4* e3 = (const f32x4*)(emb + ((size_t)k << 16) + ((size_t)bi.w << 6));
    size_t base = (((size_t)(b * CCH + k * DIM)) << 13) + s;

    float sq = 0.f;
#pragma unroll
    for (int j = 0; j < 16; ++j) {
        f32x4 q0 = e0[j], q1 = e1[j], q2 = e2[j], q3 = e3[j];
#pragma unroll
        for (int i = 0; i < 4; ++i) {
            int d = j * 4 + i;
            f32x4 zv = *(const f32x4*)(z + base + ((size_t)d << 13));
            f32x4 ov = {q0[i], q1[i], q2[i], q3[i]};
            *(f32x4*)(out + base + ((size_t)d << 13)) = ov;
            f32x4 df = zv - ov;
            sq = fmaf(df[0], df[0], sq);
            sq = fmaf(df[1], df[1], sq);
            sq = fmaf(df[2], df[2], sq);
            sq = fmaf(df[3], df[3], sq);
        }
    }

    out[ENC_OFF + (size_t)(n0 + 0) * NBOOKS + k] = (float)bi.x;
    out[ENC_OFF + (size_t)(n0 + 1) * NBOOKS + k] = (float)bi.y;
    out[ENC_OFF + (size_t)(n0 + 2) * NBOOKS + k] = (float)bi.z;
    out[ENC_OFF + (size_t)(n0 + 3) * NBOOKS + k] = (float)bi.w;
    atomicAdd(&counts[(k << 10) + bi.x], 1);
    atomicAdd(&counts[(k << 10) + bi.y], 1);
    atomicAdd(&counts[(k << 10) + bi.z], 1);
    atomicAdd(&counts[(k << 10) + bi.w], 1);

    for (int off = 32; off; off >>= 1) sq += __shfl_down(sq, off, 64);
    __shared__ float red[4];
    if ((tid & 63) == 0) red[tid >> 6] = sq;
    __syncthreads();
    if (tid == 0)
        partial[blockIdx.y * gridDim.x + blockIdx.x] = (red[0] + red[1]) + (red[2] + red[3]);
}

// ---------------------------------------------------------------- finalize
__global__ void __launch_bounds__(256) k_fin(
        const int* __restrict__ counts, const float* __restrict__ partial,
        float* __restrict__ out) {
    __shared__ float sh[256];
    int tid = threadIdx.x;

    sh[tid] = tid < 128 ? partial[tid] : 0.f;   // 32 blocks x 4 books
    __syncthreads();
    for (int off = 128; off; off >>= 1) {
        if (tid < off) sh[tid] += sh[tid + off];
        __syncthreads();
    }
    if (tid == 0) out[LOSS_OFF] = 0.25f * sh[0] / 8388608.f;

    float psum = 0.f;
    for (int k = 0; k < NBOOKS; ++k) {
        float h = 0.f;
        for (int c = tid; c < CODES; c += 256) {
            float p = (float)counts[(k << 10) + c] * (1.f / 32768.f);
            h += p * logf(p + 1e-10f);
        }
        __syncthreads();
        sh[tid] = h;
        __syncthreads();
        for (int off = 128; off; off >>= 1) {
            if (tid < off) sh[tid] += sh[tid + off];
            __syncthreads();
        }
        if (tid == 0) psum += expf(-sh[0]);
        __syncthreads();
    }
    if (tid == 0) out[PERP_OFF] = psum * (1.f / NBOOKS);
}

// ----------------------------------------------------------------
extern "C" void kernel_launch(void* const* d_in, const int* in_sizes, int n_in,
                              void* d_out, int out_size, void* d_ws, size_t ws_size,
                              hipStream_t stream) {
    const float* z   = (const float*)d_in[0];
    const float* emb = (const float*)d_in[1];
    float* out = (float*)d_out;
    char* ws = (char*)d_ws;

    float*    e2       = (float*)(ws + WS_E2);
    _Float16* ehi      = (_Float16*)(ws + WS_EHI);
    _Float16* elo      = (_Float16*)(ws + WS_ELO);
    int*      idxbuf   = (int*)(ws + WS_IDX);
    int*      counts   = (int*)(ws + WS_CNT);
    float*    partial  = (float*)(ws + WS_PART);
    int*      flagcnt  = (int*)(ws + WS_FLAGCNT);
    int*      flaglist = (int*)(ws + WS_FLAGS);

    k_eprep2<<<16, 256, 0, stream>>>(emb, e2, ehi, elo, counts, flagcnt);

    dim3 agrid(NPOS / 256, NBOOKS);
    k_argmin_mfma<<<agrid, 256, 0, stream>>>(z, e2, ehi, elo, idxbuf, flagcnt, flaglist);
    k_rescore<<<2048, 256, 0, stream>>>(z, emb, e2, flagcnt, flaglist, idxbuf);

    dim3 qgrid(NPOS / 1024, NBOOKS);
    k_quant<<<qgrid, 256, 0, stream>>>(z, emb, idxbuf, out, counts, partial);
    k_fin<<<1, 256, 0, stream>>>(counts, partial, out);
}

// Round 10
// 117.667 us; speedup vs baseline: 1.4179x; 1.4179x over previous
//
#include <hip/hip_runtime.h>

// Problem constants
#define NBOOKS 4
#define CODES  1024
#define DIM    64
#define NPOS   32768          // B*T*H*W
#define CCH    256            // NB*DIM (channel dim of z)
#define ENC_OFF  8388608
#define LOSS_OFF 8519680
#define PERP_OFF 8519681

// workspace byte offsets
#define WS_E2      0              // 4096 f32 (raw ||e||^2)
#define WS_EHI     16384          // 4096*64 f16 = 512 KB  (hi of -2*e)
#define WS_ELO     540672         // 512 KB                 (lo of -2*e)
#define WS_IDX     1064960        // 131072 int
#define WS_CNT     1589248        // 4096 int
#define WS_PART    1605632        // 128 f32
#define WS_FLAGCNT 1607680        // 1 int
#define WS_FLAGS   1607696        // 131072 int

typedef _Float16 f16x8 __attribute__((ext_vector_type(8)));
typedef _Float16 f16x4 __attribute__((ext_vector_type(4)));
typedef float    f32x4 __attribute__((ext_vector_type(4)));

// ------------------------------------------- prep: e2, hi/lo f16(-2e), zeroing
__global__ void k_eprep2(const float* __restrict__ emb, float* __restrict__ e2,
                         _Float16* __restrict__ ehi, _Float16* __restrict__ elo,
                         int* __restrict__ counts, int* __restrict__ flagcnt) {
    int i = blockIdx.x * 256 + threadIdx.x;            // row 0..4095 = k*1024+c
    counts[i] = 0;
    if (i == 0) *flagcnt = 0;
    const float4* e = (const float4*)(emb + ((size_t)i << 6));
    _Float16* hp = ehi + ((size_t)i << 6);
    _Float16* lp = elo + ((size_t)i << 6);
    float s = 0.f;
#pragma unroll
    for (int j = 0; j < 16; ++j) {
        float4 v = e[j];
        s += v.x * v.x + v.y * v.y + v.z * v.z + v.w * v.w;
        f16x4 hv, lv;
        float m;
        m = -2.f * v.x; hv[0] = (_Float16)m; lv[0] = (_Float16)(m - (float)hv[0]);
        m = -2.f * v.y; hv[1] = (_Float16)m; lv[1] = (_Float16)(m - (float)hv[1]);
        m = -2.f * v.z; hv[2] = (_Float16)m; lv[2] = (_Float16)(m - (float)hv[2]);
        m = -2.f * v.w; hv[3] = (_Float16)m; lv[3] = (_Float16)(m - (float)hv[3]);
        *(f16x4*)&hp[j * 4] = hv;
        *(f16x4*)&lp[j * 4] = lv;
    }
    e2[i] = s;           // raw; argmin adds per-position (||x||^2 + 1)
}

// ---------------------------------------------------------------- MFMA argmin v6
// Block = 128 positions x all 1024 codes, one book; 4 waves x 32 pos each.
// Grid 1024 -> 4 blocks/CU (16 waves/CU) so MFMA hides barrier+VALU phases.
// X direct global->regs; acc init = e2 + ||x||^2 + 1 (true dist + 1, positive,
// small magnitude -> tight key granule -> few flags).
// E streamed in 32-code chunks (8 KB hi+lo), 3-buffer, 1 barrier/chunk,
// XOR-swizzled write+read. Packed key = (score_bits & ~63) | kit.
__global__ void __launch_bounds__(256, 4) k_argmin_mfma(
        const float* __restrict__ z, const float* __restrict__ e2g,
        const _Float16* __restrict__ ehi, const _Float16* __restrict__ elo,
        int* __restrict__ idxbuf, int* __restrict__ flagcnt,
        int* __restrict__ flaglist) {
    __shared__ __attribute__((aligned(16))) char sE[3][8192];  // hi[0,4K) lo[4K,8K)

    int tid = threadIdx.x;
    int wave = tid >> 6, lane = tid & 63;
    int lrow = lane >> 4, lcol = lane & 15;
    int k = blockIdx.y;
    int posbase = blockIdx.x * 128;
    int b = posbase >> 13, s0 = posbase & 8191;
    int wb = wave * 32;

    // ---- X fragments straight into registers + per-position ||x||^2
    const float* zb = z + (((size_t)(b * CCH + k * DIM)) << 13) + s0 + wb;
    f16x8 Xh[2][2], Xl[2][2];
    float X2[2];                          // ||x||^2 + 1 for pos pt*16+lcol
#pragma unroll
    for (int pt = 0; pt < 2; ++pt) {
        float sq = 0.f;
#pragma unroll
        for (int kc = 0; kc < 2; ++kc) {
            f16x8 hv, lv;
#pragma unroll
            for (int e = 0; e < 8; ++e) {
                int d = kc * 32 + lrow * 8 + e;
                float f = zb[((size_t)d << 13) + pt * 16 + lcol];
                sq = fmaf(f, f, sq);
                _Float16 h = (_Float16)f;
                hv[e] = h;
                lv[e] = (_Float16)(f - (float)h);
            }
            Xh[pt][kc] = hv; Xl[pt][kc] = lv;
        }
        sq += __shfl_xor(sq, 16);
        sq += __shfl_xor(sq, 32);
        X2[pt] = sq + 1.0f;
    }

    // ---- E staging params: thread moves 32 B (two swizzled 16B pieces)/chunk
    int half = tid >> 7;                  // 0: hi, 1: lo
    int u = tid & 127;
    int r = u >> 2, q = u & 3;            // code row 0..31, 32B quarter 0..3
    const char* bookh = (const char*)((half ? elo : ehi) + ((size_t)k << 16));
    const char* src0 = bookh + r * 128 + q * 32;          // + chunk*4096
    int c0 = 2 * q, c1 = 2 * q + 1;
    int w0 = half * 4096 + r * 128 + ((c0 ^ (r & 7)) << 4);
    int w1 = half * 4096 + r * 128 + ((c1 ^ (r & 7)) << 4);

    const float* e2k = e2g + (k << 10);

    // prologue: stage chunk 0 into buffer 0
    {
        f16x8 v0 = *(const f16x8*)(src0);
        f16x8 v1 = *(const f16x8*)(src0 + 16);
        *(f16x8*)&sE[0][w0] = v0;
        *(f16x8*)&sE[0][w1] = v1;
    }

    unsigned m1[2][4], m2[2][4];
#pragma unroll
    for (int pt = 0; pt < 2; ++pt)
#pragma unroll
        for (int rr = 0; rr < 4; ++rr) { m1[pt][rr] = 0x7F7FFFFFu; m2[pt][rr] = 0x7F7FFFFFu; }

    int sx = (lcol & 7) << 4;
    int o0 = (lrow << 4) ^ sx;            // K-chunk 0 (dims 0..31)
    int o1 = ((4 + lrow) << 4) ^ sx;      // K-chunk 1 (dims 32..63)
    int rbase = lcol << 7;                // code row stride 128 B (+ st*2048)

    int cur = 0, nxt = 1, fre = 2;
    for (int it = 0; it < 32; ++it) {
        f16x8 nv0, nv1;
        bool has = it < 31;
        if (has) {
            const char* sp = src0 + (size_t)(it + 1) * 4096;
            nv0 = *(const f16x8*)(sp);
            nv1 = *(const f16x8*)(sp + 16);
        }
        __syncthreads();
        const char* sc = sE[cur];
#pragma unroll
        for (int st = 0; st < 2; ++st) {
            f32x4 e2v = *(const f32x4*)(e2k + it * 32 + st * 16 + lrow * 4);
            const char* rb = sc + st * 2048 + rbase;
            f16x8 eh0 = *(const f16x8*)(rb + o0);
            f16x8 eh1 = *(const f16x8*)(rb + o1);
            f16x8 el0 = *(const f16x8*)(rb + 4096 + o0);
            f16x8 el1 = *(const f16x8*)(rb + 4096 + o1);
            unsigned kit = (unsigned)(it * 2 + st);
#pragma unroll
            for (int pt = 0; pt < 2; ++pt) {
                f32x4 acc = e2v + X2[pt];     // score = ||x-e||^2 + 1 (positive)
                acc = __builtin_amdgcn_mfma_f32_16x16x32_f16(eh0, Xh[pt][0], acc, 0, 0, 0);
                acc = __builtin_amdgcn_mfma_f32_16x16x32_f16(eh0, Xl[pt][0], acc, 0, 0, 0);
                acc = __builtin_amdgcn_mfma_f32_16x16x32_f16(el0, Xh[pt][0], acc, 0, 0, 0);
                acc = __builtin_amdgcn_mfma_f32_16x16x32_f16(eh1, Xh[pt][1], acc, 0, 0, 0);
                acc = __builtin_amdgcn_mfma_f32_16x16x32_f16(eh1, Xl[pt][1], acc, 0, 0, 0);
                acc = __builtin_amdgcn_mfma_f32_16x16x32_f16(el1, Xh[pt][1], acc, 0, 0, 0);
#pragma unroll
                for (int rr = 0; rr < 4; ++rr) {
                    unsigned key = (__float_as_uint(acc[rr]) & 0xFFFFFFC0u) | kit;
                    unsigned mx = key > m1[pt][rr] ? key : m1[pt][rr];
                    m2[pt][rr] = m2[pt][rr] < mx ? m2[pt][rr] : mx;
                    m1[pt][rr] = m1[pt][rr] < key ? m1[pt][rr] : key;
                }
            }
        }
        if (has) {
            *(f16x8*)&sE[nxt][w0] = nv0;
            *(f16x8*)&sE[nxt][w1] = nv1;
        }
        int t = cur; cur = nxt; nxt = fre; fre = t;
    }

    // ---- within-thread merge over r slots (exact, index tie-break)
    float F1[2], F2[2]; int I1[2];
#pragma unroll
    for (int pt = 0; pt < 2; ++pt) {
        float f1 = 3.4e38f, f2 = 3.4e38f; int i1 = 0;
#pragma unroll
        for (int rr = 0; rr < 4; ++rr) {
            float f = __uint_as_float(m1[pt][rr] & 0xFFFFFFC0u);
            int   c = (int)(m1[pt][rr] & 63u) * 16 + lrow * 4 + rr;
            float g = __uint_as_float(m2[pt][rr] & 0xFFFFFFC0u);
            bool take = (f < f1) || (f == f1 && c < i1);
            float loser = take ? f1 : f;
            f2 = fminf(fminf(f2, g), loser);
            if (take) { f1 = f; i1 = c; }
        }
        F1[pt] = f1; F2[pt] = f2; I1[pt] = i1;
    }

    // ---- merge across lrow groups (4 lanes hold same position)
#pragma unroll
    for (int off = 16; off < 64; off <<= 1) {
#pragma unroll
        for (int pt = 0; pt < 2; ++pt) {
            float om1 = __shfl_xor(F1[pt], off);
            float om2 = __shfl_xor(F2[pt], off);
            int   oi  = __shfl_xor(I1[pt], off);
            bool take = (om1 < F1[pt]) || (om1 == F1[pt] && oi < I1[pt]);
            float loser = take ? F1[pt] : om1;
            F2[pt] = fminf(fminf(F2[pt], om2), loser);
            if (take) { F1[pt] = om1; I1[pt] = oi; }
        }
    }

    // ---- write idx, flag near-ties: adaptive margin
    if (lane < 16) {
#pragma unroll
        for (int pt = 0; pt < 2; ++pt) {
            int n = posbase + wb + pt * 16 + lane;
            idxbuf[(k << 15) + n] = I1[pt];
            float thr = fmaf(F1[pt], 3.2e-5f, 2.0e-3f);
            if (F2[pt] - F1[pt] < thr) {
                int slot = atomicAdd(flagcnt, 1);
                flaglist[slot] = (k << 15) + n;
            }
        }
    }
}

// ---------------------------------------------------------------- rescore v4
// One BLOCK (256 threads) per flagged position: each thread owns 4 codes
// (64 f32x4 loads, 4 independent chains) -> deep load batching instead of the
// previous half-wave serial chain. Exact fp32, first-min tie-break.
__global__ void __launch_bounds__(256) k_rescore(
        const float* __restrict__ z, const float* __restrict__ emb,
        const float* __restrict__ e2g, const int* __restrict__ flagcnt,
        const int* __restrict__ flaglist, int* __restrict__ idxbuf) {
    __shared__ __attribute__((aligned(16))) float xsh[64];
    __shared__ float wbest[4];
    __shared__ int   wbi[4];
    int tid = threadIdx.x;
    int wave = tid >> 6, lane = tid & 63;
    int nf = *flagcnt;
    for (int e = blockIdx.x; e < nf; e += gridDim.x) {
        int gp = flaglist[e];
        int kk = gp >> 15, n = gp & 32767;
        int bb = n >> 13, s = n & 8191;
        __syncthreads();                   // xsh/wbest reuse guard
        if (tid < 64)
            xsh[tid] = z[(((size_t)(bb * CCH + kk * DIM + tid)) << 13) + s];
        __syncthreads();

        const f32x4* ek4 = (const f32x4*)(emb + ((size_t)kk << 16));
        const float* ee  = e2g + (kk << 10);
        const f32x4* xr4 = (const f32x4*)xsh;
        float best = 3.4e38f; int bi = 0;
#pragma unroll
        for (int cc = 0; cc < 4; ++cc) {
            int c = cc * 256 + tid;
            const f32x4* ev = ek4 + (size_t)c * 16;
            float a0 = 0.f, a1 = 0.f, a2 = 0.f, a3 = 0.f;
#pragma unroll
            for (int j = 0; j < 16; ++j) {
                f32x4 xv = xr4[j];
                f32x4 qv = ev[j];
                a0 = fmaf(xv[0], qv[0], a0); a1 = fmaf(xv[1], qv[1], a1);
                a2 = fmaf(xv[2], qv[2], a2); a3 = fmaf(xv[3], qv[3], a3);
            }
            float dist = fmaf(-2.f, (a0 + a1) + (a2 + a3), ee[c]);
            if (dist < best) { best = dist; bi = c; }    // cc ascending => first-min
        }
#pragma unroll
        for (int off = 1; off < 64; off <<= 1) {
            float ob = __shfl_xor(best, off);
            int   oi = __shfl_xor(bi, off);
            if (ob < best || (ob == best && oi < bi)) { best = ob; bi = oi; }
        }
        if (lane == 0) { wbest[wave] = best; wbi[wave] = bi; }
        __syncthreads();
        if (tid == 0) {
            float b0 = wbest[0]; int i0 = wbi[0];
#pragma unroll
            for (int w = 1; w < 4; ++w) {
                float bw = wbest[w]; int iw = wbi[w];
                if (bw < b0 || (bw == b0 && iw < i0)) { b0 = bw; i0 = iw; }
            }
            idxbuf[gp] = i0;
        }
    }
}

// ---------------------------------------------------------------- gather+loss
// 4 consecutive positions per thread -> float4 z loads / q stores.
__global__ void __launch_bounds__(256) k_quant(
        const float* __restrict__ z, const float* __restrict__ emb,
        const int* __restrict__ idxbuf, float* __restrict__ out,
        int* __restrict__ counts, float* __restrict__ partial) {
    int tid = threadIdx.x;
    int q = blockIdx.x * 256 + tid;       // quad index
    int n0 = q * 4;
    int k = blockIdx.y;
    int b = n0 >> 13;
    int s = n0 & 8191;

    int4 bi = *(const int4*)&idxbuf[(k << 15) + n0];
    const f32x4* e0 = (const f32x4*)(emb + ((size_t)k << 16) + ((size_t)bi.x << 6));
    const f32x4* e1 = (const f32x4*)(emb + ((size_t)k << 16) + ((size_t)bi.y << 6));
    const f32x4* e2 = (const f32x4*)(emb + ((size_t)k << 16) + ((size_t)bi.z << 6));
    const f32x4* e3 = (const f32x4*)(emb + ((size_t)k << 16) + ((size_t)bi.w << 6));
    size_t base = (((size_t)(b * CCH + k * DIM)) << 13) + s;

    float sq = 0.f;
#pragma unroll
    for (int j = 0; j < 16; ++j) {
        f32x4 q0 = e0[j], q1 = e1[j], q2 = e2[j], q3 = e3[j];
#pragma unroll
        for (int i = 0; i < 4; ++i) {
            int d = j * 4 + i;
            f32x4 zv = *(const f32x4*)(z + base + ((size_t)d << 13));
            f32x4 ov = {q0[i], q1[i], q2[i], q3[i]};
            *(f32x4*)(out + base + ((size_t)d << 13)) = ov;
            f32x4 df = zv - ov;
            sq = fmaf(df[0], df[0], sq);
            sq = fmaf(df[1], df[1], sq);
            sq = fmaf(df[2], df[2], sq);
            sq = fmaf(df[3], df[3], sq);
        }
    }

    out[ENC_OFF + (size_t)(n0 + 0) * NBOOKS + k] = (float)bi.x;
    out[ENC_OFF + (size_t)(n0 + 1) * NBOOKS + k] = (float)bi.y;
    out[ENC_OFF + (size_t)(n0 + 2) * NBOOKS + k] = (float)bi.z;
    out[ENC_OFF + (size_t)(n0 + 3) * NBOOKS + k] = (float)bi.w;
    atomicAdd(&counts[(k << 10) + bi.x], 1);
    atomicAdd(&counts[(k << 10) + bi.y], 1);
    atomicAdd(&counts[(k << 10) + bi.z], 1);
    atomicAdd(&counts[(k << 10) + bi.w], 1);

    for (int off = 32; off; off >>= 1) sq += __shfl_down(sq, off, 64);
    __shared__ float red[4];
    if ((tid & 63) == 0) red[tid >> 6] = sq;
    __syncthreads();
    if (tid == 0)
        partial[blockIdx.y * gridDim.x + blockIdx.x] = (red[0] + red[1]) + (red[2] + red[3]);
}

// ---------------------------------------------------------------- finalize
__global__ void __launch_bounds__(256) k_fin(
        const int* __restrict__ counts, const float* __restrict__ partial,
        float* __restrict__ out) {
    __shared__ float sh[256];
    int tid = threadIdx.x;

    sh[tid] = tid < 128 ? partial[tid] : 0.f;   // 32 blocks x 4 books
    __syncthreads();
    for (int off = 128; off; off >>= 1) {
        if (tid < off) sh[tid] += sh[tid + off];
        __syncthreads();
    }
    if (tid == 0) out[LOSS_OFF] = 0.25f * sh[0] / 8388608.f;

    float psum = 0.f;
    for (int k = 0; k < NBOOKS; ++k) {
        float h = 0.f;
        for (int c = tid; c < CODES; c += 256) {
            float p = (float)counts[(k << 10) + c] * (1.f / 32768.f);
            h += p * logf(p + 1e-10f);
        }
        __syncthreads();
        sh[tid] = h;
        __syncthreads();
        for (int off = 128; off; off >>= 1) {
            if (tid < off) sh[tid] += sh[tid + off];
            __syncthreads();
        }
        if (tid == 0) psum += expf(-sh[0]);
        __syncthreads();
    }
    if (tid == 0) out[PERP_OFF] = psum * (1.f / NBOOKS);
}

// ----------------------------------------------------------------
extern "C" void kernel_launch(void* const* d_in, const int* in_sizes, int n_in,
                              void* d_out, int out_size, void* d_ws, size_t ws_size,
                              hipStream_t stream) {
    const float* z   = (const float*)d_in[0];
    const float* emb = (const float*)d_in[1];
    float* out = (float*)d_out;
    char* ws = (char*)d_ws;

    float*    e2       = (float*)(ws + WS_E2);
    _Float16* ehi      = (_Float16*)(ws + WS_EHI);
    _Float16* elo      = (_Float16*)(ws + WS_ELO);
    int*      idxbuf   = (int*)(ws + WS_IDX);
    int*      counts   = (int*)(ws + WS_CNT);
    float*    partial  = (float*)(ws + WS_PART);
    int*      flagcnt  = (int*)(ws + WS_FLAGCNT);
    int*      flaglist = (int*)(ws + WS_FLAGS);

    k_eprep2<<<16, 256, 0, stream>>>(emb, e2, ehi, elo, counts, flagcnt);

    dim3 agrid(NPOS / 128, NBOOKS);
    k_argmin_mfma<<<agrid, 256, 0, stream>>>(z, e2, ehi, elo, idxbuf, flagcnt, flaglist);
    k_rescore<<<1024, 256, 0, stream>>>(z, emb, e2, flagcnt, flaglist, idxbuf);

    dim3 qgrid(NPOS / 1024, NBOOKS);
    k_quant<<<qgrid, 256, 0, stream>>>(z, emb, idxbuf, out, counts, partial);
    k_fin<<<1, 256, 0, stream>>>(counts, partial, out);
}